// Round 12
// baseline (298.074 us; speedup 1.0000x reference)
//
#include <hip/hip_runtime.h>
#include <cstdint>

typedef uint16_t u16;
typedef unsigned int u32;
typedef __attribute__((ext_vector_type(8))) short bf16x8;
typedef __attribute__((ext_vector_type(4))) float f32x4;

union U4V { uint4 u; bf16x8 v; };

#define EPSBN 1e-5f

__device__ __forceinline__ float bf2f(u16 h) {
  return __uint_as_float(((unsigned)h) << 16);
}
__device__ __forceinline__ u16 f2bf(float f) {
  unsigned u = __float_as_uint(f);
  unsigned r = u + 0x7fffu + ((u >> 16) & 1u);
  return (u16)(r >> 16);
}

// ---------------------------------------------------------------------------
// K0: W5 -> bf16 hi/lo fragment-linear; W2/W3/W4 -> fragment-linear hi/lo
// for k1's MFMA layers; W1 + folded BN scale/shift into Wf.
// ---------------------------------------------------------------------------
__global__ void k0_prep(const float* __restrict__ W5,
                        const float* __restrict__ W1, const float* __restrict__ W2,
                        const float* __restrict__ W3, const float* __restrict__ W4,
                        const float* g1, const float* b1, const float* m1, const float* v1,
                        const float* g2, const float* b2, const float* m2, const float* v2,
                        const float* g3, const float* b3, const float* m3, const float* v3,
                        const float* g4, const float* b4, const float* m4, const float* v4,
                        u16* __restrict__ W5h, u16* __restrict__ W5l,
                        u16* __restrict__ W2h, u16* __restrict__ W2l,
                        u16* __restrict__ W3h, u16* __restrict__ W3l,
                        u16* __restrict__ W4h, u16* __restrict__ W4l,
                        float* __restrict__ Wf)
{
  int idx = blockIdx.x * 256 + threadIdx.x;
  if (idx < 131072) {
    int f = idx;
    int j = f & 7, l15 = (f >> 3) & 15, quad = (f >> 7) & 3, ks = (f >> 9) & 3, g = f >> 11;
    float w = W5[(g * 16 + l15) * 128 + ks * 32 + quad * 8 + j];
    u16 hi = f2bf(w);
    W5h[f] = hi;
    W5l[f] = f2bf(w - bf2f(hi));
    return;
  }
  int j = idx - 131072;
  if (j < 16384) {
    const float* src; u16 *dh, *dl; int f;
    if (j < 4096)      { src = W2; dh = W2h; dl = W2l; f = j; }
    else if (j < 8192) { src = W3; dh = W3h; dl = W3l; f = j - 4096; }
    else               { src = W4; dh = W4h; dl = W4l; f = j - 8192; }
    int jj = f & 7;
    int lane = (f >> 3) & 63;
    int t = f >> 9;            // tn*2 + ks
    int ks = t & 1, tn = t >> 1;
    int l15 = lane & 15, quad = lane >> 4;
    float w = src[(tn * 16 + l15) * 64 + ks * 32 + quad * 8 + jj];
    u16 hi = f2bf(w);
    dh[f] = hi;
    dl[f] = f2bf(w - bf2f(hi));
  } else if (j < 16576) {
    Wf[j] = W1[j - 16384];
  } else if (j < 16896) {
    int t = j - 16576;
    const float *g, *bb, *mm, *vv; int ch;
    if (t < 64)       { g = g1; bb = b1; mm = m1; vv = v1; ch = t;       }
    else if (t < 128) { g = g2; bb = b2; mm = m2; vv = v2; ch = t - 64;  }
    else if (t < 192) { g = g3; bb = b3; mm = m3; vv = v3; ch = t - 128; }
    else              { g = g4; bb = b4; mm = m4; vv = v4; ch = t - 192; }
    float s = g[ch] / sqrtf(vv[ch] + EPSBN);
    Wf[16576 + t] = s;
    Wf[16896 + t] = bb[ch] - mm[ch] * s;
  }
}

// ---------------------------------------------------------------------------
// K1 v2 (r10 verbatim): layers 2-4 on MFMA, wave-private LDS transpose,
// h as hi/lo bf16 pairs. Output H4 hi/lo, layout [b][kg][n][8].
// ---------------------------------------------------------------------------
__global__ __launch_bounds__(128, 2) void k1_conv(
    const float* __restrict__ x, const float* __restrict__ Wf,
    const u16* __restrict__ W2h, const u16* __restrict__ W2l,
    const u16* __restrict__ W3h, const u16* __restrict__ W3l,
    const u16* __restrict__ W4h, const u16* __restrict__ W4l,
    u16* __restrict__ H4a, u16* __restrict__ H4b)
{
  __shared__ u32 T[2][64 * 68];
  __shared__ float P1[832];
  const int tid = threadIdx.x;
  const int w = tid >> 6, lane = tid & 63;
  const int l15 = lane & 15, quad = lane >> 4;
  const int base = blockIdx.x * 128 + w * 64;
  const int b = base >> 13, n0 = base & 8191;

  for (int i = tid; i < 832; i += 128)
    P1[i] = (i < 192) ? Wf[16384 + i]
          : (i < 512) ? Wf[16576 + (i - 192)]
                      : Wf[16896 + (i - 512)];
  __syncthreads();
  u32* Tw = &T[w][0];
  const float* SCs = &P1[192];
  const float* SHs = &P1[512];
  const f32x4 vzero = {0.f, 0.f, 0.f, 0.f};

  float xl0 = x[(b * 3 + 0) * 8192 + n0 + lane];
  float xl1 = x[(b * 3 + 1) * 8192 + n0 + lane];
  float xl2 = x[(b * 3 + 2) * 8192 + n0 + lane];
  float xs0[4], xs1[4], xs2[4];
  #pragma unroll
  for (int tm = 0; tm < 4; ++tm) {
    xs0[tm] = __shfl(xl0, tm * 16 + l15, 64);
    xs1[tm] = __shfl(xl1, tm * 16 + l15, 64);
    xs2[tm] = __shfl(xl2, tm * 16 + l15, 64);
  }
  bf16x8 ah[2][4], al[2][4];
  #pragma unroll
  for (int ks = 0; ks < 2; ++ks)
    #pragma unroll
    for (int tm = 0; tm < 4; ++tm) {
      u32 hp[4], lp[4];
      #pragma unroll
      for (int jp = 0; jp < 4; ++jp) {
        u32 hpair = 0, lpair = 0;
        #pragma unroll
        for (int e = 0; e < 2; ++e) {
          int ch = ks * 32 + quad * 8 + jp * 2 + e;
          float c = P1[ch * 3] * xs0[tm];
          c = fmaf(P1[ch * 3 + 1], xs1[tm], c);
          c = fmaf(P1[ch * 3 + 2], xs2[tm], c);
          float v = fmaxf(0.f, fmaf(c, SCs[ch], SHs[ch]));
          u16 hi = f2bf(v); float er = v - bf2f(hi); u16 lo = f2bf(er);
          hpair |= ((u32)hi) << (16 * e);
          lpair |= ((u32)lo) << (16 * e);
        }
        hp[jp] = hpair; lp[jp] = lpair;
      }
      U4V th, tl;
      th.u.x = hp[0]; th.u.y = hp[1]; th.u.z = hp[2]; th.u.w = hp[3];
      tl.u.x = lp[0]; tl.u.y = lp[1]; tl.u.z = lp[2]; tl.u.w = lp[3];
      ah[ks][tm] = th.v; al[ks][tm] = tl.v;
    }

  // ---- L2
  {
    f32x4 acc[4][4];
    #pragma unroll
    for (int tm = 0; tm < 4; ++tm)
      #pragma unroll
      for (int tn = 0; tn < 4; ++tn) acc[tm][tn] = vzero;
    #pragma unroll
    for (int ks = 0; ks < 2; ++ks) {
      bf16x8 bh[4], bl[4];
      #pragma unroll
      for (int tn = 0; tn < 4; ++tn) {
        int idx = ((tn * 2 + ks) * 64 + lane) * 8;
        bh[tn] = *(const bf16x8*)&W2h[idx];
        bl[tn] = *(const bf16x8*)&W2l[idx];
      }
      #pragma unroll
      for (int tm = 0; tm < 4; ++tm)
        #pragma unroll
        for (int tn = 0; tn < 4; ++tn) {
          acc[tm][tn] = __builtin_amdgcn_mfma_f32_16x16x32_bf16(ah[ks][tm], bh[tn], acc[tm][tn], 0, 0, 0);
          acc[tm][tn] = __builtin_amdgcn_mfma_f32_16x16x32_bf16(ah[ks][tm], bl[tn], acc[tm][tn], 0, 0, 0);
          acc[tm][tn] = __builtin_amdgcn_mfma_f32_16x16x32_bf16(al[ks][tm], bh[tn], acc[tm][tn], 0, 0, 0);
        }
    }
    #pragma unroll
    for (int tn = 0; tn < 4; ++tn) {
      int ch = tn * 16 + l15;
      float sc = SCs[64 + ch], sh = SHs[64 + ch];
      #pragma unroll
      for (int tm = 0; tm < 4; ++tm)
        #pragma unroll
        for (int r = 0; r < 4; ++r) {
          float v = fmaxf(0.f, fmaf(acc[tm][tn][r], sc, sh));
          u16 hi = f2bf(v); float er = v - bf2f(hi); u16 lo = f2bf(er);
          Tw[(tm * 16 + quad * 4 + r) * 68 + ch] = (u32)hi | ((u32)lo << 16);
        }
    }
  }

  // ---- L3
  #pragma unroll
  for (int ks = 0; ks < 2; ++ks)
    #pragma unroll
    for (int tm = 0; tm < 4; ++tm) {
      const uint4 p0 = *(const uint4*)&Tw[(tm * 16 + l15) * 68 + ks * 32 + quad * 8];
      const uint4 p1 = *(const uint4*)&Tw[(tm * 16 + l15) * 68 + ks * 32 + quad * 8 + 4];
      U4V th, tl;
      th.u.x = (p0.x & 0xffffu) | (p0.y << 16);
      th.u.y = (p0.z & 0xffffu) | (p0.w << 16);
      th.u.z = (p1.x & 0xffffu) | (p1.y << 16);
      th.u.w = (p1.z & 0xffffu) | (p1.w << 16);
      tl.u.x = (p0.x >> 16) | (p0.y & 0xffff0000u);
      tl.u.y = (p0.z >> 16) | (p0.w & 0xffff0000u);
      tl.u.z = (p1.x >> 16) | (p1.y & 0xffff0000u);
      tl.u.w = (p1.z >> 16) | (p1.w & 0xffff0000u);
      ah[ks][tm] = th.v; al[ks][tm] = tl.v;
    }
  {
    f32x4 acc[4][4];
    #pragma unroll
    for (int tm = 0; tm < 4; ++tm)
      #pragma unroll
      for (int tn = 0; tn < 4; ++tn) acc[tm][tn] = vzero;
    #pragma unroll
    for (int ks = 0; ks < 2; ++ks) {
      bf16x8 bh[4], bl[4];
      #pragma unroll
      for (int tn = 0; tn < 4; ++tn) {
        int idx = ((tn * 2 + ks) * 64 + lane) * 8;
        bh[tn] = *(const bf16x8*)&W3h[idx];
        bl[tn] = *(const bf16x8*)&W3l[idx];
      }
      #pragma unroll
      for (int tm = 0; tm < 4; ++tm)
        #pragma unroll
        for (int tn = 0; tn < 4; ++tn) {
          acc[tm][tn] = __builtin_amdgcn_mfma_f32_16x16x32_bf16(ah[ks][tm], bh[tn], acc[tm][tn], 0, 0, 0);
          acc[tm][tn] = __builtin_amdgcn_mfma_f32_16x16x32_bf16(ah[ks][tm], bl[tn], acc[tm][tn], 0, 0, 0);
          acc[tm][tn] = __builtin_amdgcn_mfma_f32_16x16x32_bf16(al[ks][tm], bh[tn], acc[tm][tn], 0, 0, 0);
        }
    }
    #pragma unroll
    for (int tn = 0; tn < 4; ++tn) {
      int ch = tn * 16 + l15;
      float sc = SCs[128 + ch], sh = SHs[128 + ch];
      #pragma unroll
      for (int tm = 0; tm < 4; ++tm)
        #pragma unroll
        for (int r = 0; r < 4; ++r) {
          float v = fmaxf(0.f, fmaf(acc[tm][tn][r], sc, sh));
          u16 hi = f2bf(v); float er = v - bf2f(hi); u16 lo = f2bf(er);
          Tw[(tm * 16 + quad * 4 + r) * 68 + ch] = (u32)hi | ((u32)lo << 16);
        }
    }
  }

  // ---- L4
  #pragma unroll
  for (int ks = 0; ks < 2; ++ks)
    #pragma unroll
    for (int tm = 0; tm < 4; ++tm) {
      const uint4 p0 = *(const uint4*)&Tw[(tm * 16 + l15) * 68 + ks * 32 + quad * 8];
      const uint4 p1 = *(const uint4*)&Tw[(tm * 16 + l15) * 68 + ks * 32 + quad * 8 + 4];
      U4V th, tl;
      th.u.x = (p0.x & 0xffffu) | (p0.y << 16);
      th.u.y = (p0.z & 0xffffu) | (p0.w << 16);
      th.u.z = (p1.x & 0xffffu) | (p1.y << 16);
      th.u.w = (p1.z & 0xffffu) | (p1.w << 16);
      tl.u.x = (p0.x >> 16) | (p0.y & 0xffff0000u);
      tl.u.y = (p0.z >> 16) | (p0.w & 0xffff0000u);
      tl.u.z = (p1.x >> 16) | (p1.y & 0xffff0000u);
      tl.u.w = (p1.z >> 16) | (p1.w & 0xffff0000u);
      ah[ks][tm] = th.v; al[ks][tm] = tl.v;
    }
  for (int half = 0; half < 2; ++half) {
    f32x4 acc[4][4];
    #pragma unroll
    for (int tm = 0; tm < 4; ++tm)
      #pragma unroll
      for (int tn = 0; tn < 4; ++tn) acc[tm][tn] = vzero;
    #pragma unroll
    for (int ks = 0; ks < 2; ++ks) {
      bf16x8 bh[4], bl[4];
      #pragma unroll
      for (int tn = 0; tn < 4; ++tn) {
        int idx = (((half * 4 + tn) * 2 + ks) * 64 + lane) * 8;
        bh[tn] = *(const bf16x8*)&W4h[idx];
        bl[tn] = *(const bf16x8*)&W4l[idx];
      }
      #pragma unroll
      for (int tm = 0; tm < 4; ++tm)
        #pragma unroll
        for (int tn = 0; tn < 4; ++tn) {
          acc[tm][tn] = __builtin_amdgcn_mfma_f32_16x16x32_bf16(ah[ks][tm], bh[tn], acc[tm][tn], 0, 0, 0);
          acc[tm][tn] = __builtin_amdgcn_mfma_f32_16x16x32_bf16(ah[ks][tm], bl[tn], acc[tm][tn], 0, 0, 0);
          acc[tm][tn] = __builtin_amdgcn_mfma_f32_16x16x32_bf16(al[ks][tm], bh[tn], acc[tm][tn], 0, 0, 0);
        }
    }
    #pragma unroll
    for (int tn = 0; tn < 4; ++tn) {
      int ch = half * 64 + tn * 16 + l15;
      float sc = SCs[192 + ch], sh = SHs[192 + ch];
      #pragma unroll
      for (int tm = 0; tm < 4; ++tm)
        #pragma unroll
        for (int r = 0; r < 4; ++r) {
          float v = fmaxf(0.f, fmaf(acc[tm][tn][r], sc, sh));
          u16 hi = f2bf(v); float er = v - bf2f(hi); u16 lo = f2bf(er);
          Tw[(tm * 16 + quad * 4 + r) * 68 + tn * 16 + l15] = (u32)hi | ((u32)lo << 16);
        }
    }
    #pragma unroll
    for (int kg = 0; kg < 8; ++kg) {
      const uint4 p0 = *(const uint4*)&Tw[lane * 68 + kg * 8];
      const uint4 p1 = *(const uint4*)&Tw[lane * 68 + kg * 8 + 4];
      uint4 hu, lu;
      hu.x = (p0.x & 0xffffu) | (p0.y << 16);
      hu.y = (p0.z & 0xffffu) | (p0.w << 16);
      hu.z = (p1.x & 0xffffu) | (p1.y << 16);
      hu.w = (p1.z & 0xffffu) | (p1.w << 16);
      lu.x = (p0.x >> 16) | (p0.y & 0xffff0000u);
      lu.y = (p0.z >> 16) | (p0.w & 0xffff0000u);
      lu.z = (p1.x >> 16) | (p1.y & 0xffff0000u);
      lu.w = (p1.z >> 16) | (p1.w & 0xffff0000u);
      size_t e = ((size_t)(b * 16 + half * 8 + kg) * 8192 + n0 + lane) * 8;
      *(uint4*)&H4a[e] = hu;
      *(uint4*)&H4b[e] = lu;
    }
  }
}

// ---------------------------------------------------------------------------
// K2a: r11 structure + Bl ALSO hoisted to registers -> inner loop is pure
// ds_read+MFMA (no global loads between barriers). Combined V+A budget ~256
// stays in the 2-waves/SIMD tier; LDS 64 KB keeps 2 blocks/CU.
// ---------------------------------------------------------------------------
__global__ __launch_bounds__(256, 2) void k2a_gemm(
    const u16* __restrict__ H4a, const u16* __restrict__ H4b,
    const u16* __restrict__ W5h, const u16* __restrict__ W5l,
    float* __restrict__ pmax, int* __restrict__ pidx)
{
  __shared__ u16 AA[2][2][16 * 512];   // [tile][h/l][chunk-major 16 KB]

  const int blk = blockIdx.x;
  const int nc = (blk >> 3) & 3;
  const int p  = ((blk >> 5) << 3) + (blk & 7);
  const int b  = p >> 4;
  const int ps = p & 15;
  const int tid = threadIdx.x;
  const int lane = tid & 63, wv = tid >> 6;
  const int l15 = lane & 15, quad = lane >> 4;

  bf16x8 bh[4][4], blr[4][4];
  #pragma unroll
  for (int ks = 0; ks < 4; ++ks)
    #pragma unroll
    for (int tn = 0; tn < 4; ++tn) {
      int g = nc * 16 + wv * 4 + tn;
      size_t widx = (size_t)(g * 4 + ks) * 512 + lane * 8;
      bh[ks][tn]  = *(const bf16x8*)&W5h[widx];
      blr[ks][tn] = *(const bf16x8*)&W5l[widx];
    }

  const u16* pa[4];
  const u16* pb[4];
  #pragma unroll
  for (int i = 0; i < 4; ++i) {
    int c = i * 4 + wv;
    size_t e = ((size_t)(b * 16 + c) * 8192 + ps * 512 + lane) * 8;
    pa[i] = H4a + e;
    pb[i] = H4b + e;
  }

  float runM[4]; int runI[4];
  #pragma unroll
  for (int tn = 0; tn < 4; ++tn) { runM[tn] = -3.4e38f; runI[tn] = 0; }

  const f32x4 vzero = {0.f, 0.f, 0.f, 0.f};

  for (int tp = 0; tp < 4; ++tp) {
    __syncthreads();                  // previous pair's LDS reads done
    #pragma unroll
    for (int u = 0; u < 2; ++u) {
      #pragma unroll
      for (int i = 0; i < 4; ++i) {
        int c = i * 4 + wv;
        uint4 va = *(const uint4*)(pa[i] + u * 512);
        uint4 vb = *(const uint4*)(pb[i] + u * 512);
        *(uint4*)&AA[u][0][c * 512 + lane * 8] = va;
        *(uint4*)&AA[u][1][c * 512 + lane * 8] = vb;
      }
    }
    __syncthreads();

    #pragma unroll
    for (int u = 0; u < 2; ++u) {
      const int mb = ps * 512 + tp * 128 + u * 64;
      f32x4 acc[4][4];
      #pragma unroll
      for (int tm = 0; tm < 4; ++tm)
        #pragma unroll
        for (int tn = 0; tn < 4; ++tn)
          acc[tm][tn] = vzero;

      #pragma unroll
      for (int ks = 0; ks < 4; ++ks) {
        bf16x8 afh[4], afl[4];
        #pragma unroll
        for (int tm = 0; tm < 4; ++tm) {
          int off = (ks * 4 + quad) * 512 + (tm * 16 + l15) * 8;
          afh[tm] = *(const bf16x8*)&AA[u][0][off];
          afl[tm] = *(const bf16x8*)&AA[u][1][off];
        }
        #pragma unroll
        for (int tm = 0; tm < 4; ++tm)
          #pragma unroll
          for (int tn = 0; tn < 4; ++tn) {
            acc[tm][tn] = __builtin_amdgcn_mfma_f32_16x16x32_bf16(afh[tm], bh[ks][tn],  acc[tm][tn], 0, 0, 0);
            acc[tm][tn] = __builtin_amdgcn_mfma_f32_16x16x32_bf16(afh[tm], blr[ks][tn], acc[tm][tn], 0, 0, 0);
            acc[tm][tn] = __builtin_amdgcn_mfma_f32_16x16x32_bf16(afl[tm], bh[ks][tn],  acc[tm][tn], 0, 0, 0);
          }
      }

      // argmax fold (P=8192 exact -> no bounds check; pts ascend in-thread)
      #pragma unroll
      for (int tn = 0; tn < 4; ++tn) {
        #pragma unroll
        for (int tm = 0; tm < 4; ++tm) {
          #pragma unroll
          for (int r = 0; r < 4; ++r) {
            int pt = mb + tm * 16 + (quad << 2) + r;
            float v = acc[tm][tn][r];
            if (v > runM[tn]) { runM[tn] = v; runI[tn] = pt; }
          }
        }
      }
    }

    #pragma unroll
    for (int i = 0; i < 4; ++i) { pa[i] += 1024; pb[i] += 1024; }
  }

  #pragma unroll
  for (int tn = 0; tn < 4; ++tn) {
    float rM = runM[tn]; int rI = runI[tn];
    #pragma unroll
    for (int mk = 16; mk <= 32; mk <<= 1) {
      float v2 = __shfl_xor(rM, mk, 64);
      int   i2 = __shfl_xor(rI, mk, 64);
      if (v2 > rM || (v2 == rM && i2 < rI)) { rM = v2; rI = i2; }
    }
    if (quad == 0) {
      int ch = nc * 256 + wv * 64 + tn * 16 + l15;
      size_t o = (((size_t)b * 1024 + ch) << 4) + ps;
      pmax[o] = rM; pidx[o] = rI;
    }
  }
}

// ---------------------------------------------------------------------------
// K2 generic (gathered second pass): r8 structure + Bl hoisted.
// ---------------------------------------------------------------------------
__global__ __launch_bounds__(256, 2) void k2_gemm(
    const u16* __restrict__ H4a, const u16* __restrict__ H4b,
    const u16* __restrict__ W5h, const u16* __restrict__ W5l,
    const int* __restrict__ sel,
    int P, int PS, int TPB,
    float* __restrict__ pmax, int* __restrict__ pidx)
{
  __shared__ u16 Ah[16 * 512];
  __shared__ u16 Al[16 * 512];

  const int blk = blockIdx.x;
  const int nc = (blk >> 3) & 3;
  const int p  = ((blk >> 5) << 3) + (blk & 7);
  const int b  = p / PS;
  const int ps = p % PS;
  const int tid = threadIdx.x;
  const int lane = tid & 63, wv = tid >> 6;
  const int l15 = lane & 15, quad = lane >> 4;

  bf16x8 bh[4][4], blr[4][4];
  #pragma unroll
  for (int ks = 0; ks < 4; ++ks)
    #pragma unroll
    for (int tn = 0; tn < 4; ++tn) {
      int g = nc * 16 + wv * 4 + tn;
      size_t widx = (size_t)(g * 4 + ks) * 512 + lane * 8;
      bh[ks][tn]  = *(const bf16x8*)&W5h[widx];
      blr[ks][tn] = *(const bf16x8*)&W5l[widx];
    }

  float runM[4]; int runI[4];
  #pragma unroll
  for (int tn = 0; tn < 4; ++tn) { runM[tn] = -3.4e38f; runI[tn] = 0x7FFFFFFF; }

  const f32x4 vzero = {0.f, 0.f, 0.f, 0.f};

  for (int t = 0; t < TPB; ++t) {
    const int mb = (ps * TPB + t) << 6;
    if (mb >= P) break;

    __syncthreads();
    #pragma unroll
    for (int i = 0; i < 4; ++i) {
      int c = i * 4 + wv;
      uint4 va; va.x = va.y = va.z = va.w = 0u;
      uint4 vb; vb.x = vb.y = vb.z = vb.w = 0u;
      if (sel) {
        int pt = mb + lane;
        if (pt < P) {
          int n0 = sel[b * 600 + pt] & 8191;
          size_t e = ((size_t)(b * 16 + c) * 8192 + n0) * 8;
          va = *(const uint4*)&H4a[e];
          vb = *(const uint4*)&H4b[e];
        }
      } else {
        size_t e = ((size_t)(b * 16 + c) * 8192 + (mb + lane)) * 8;
        va = *(const uint4*)&H4a[e];
        vb = *(const uint4*)&H4b[e];
      }
      *(uint4*)&Ah[c * 512 + lane * 8] = va;
      *(uint4*)&Al[c * 512 + lane * 8] = vb;
    }
    __syncthreads();

    f32x4 acc[4][4];
    #pragma unroll
    for (int tm = 0; tm < 4; ++tm)
      #pragma unroll
      for (int tn = 0; tn < 4; ++tn)
        acc[tm][tn] = vzero;

    #pragma unroll
    for (int ks = 0; ks < 4; ++ks) {
      bf16x8 afh[4], afl[4];
      #pragma unroll
      for (int tm = 0; tm < 4; ++tm) {
        int off = (ks * 4 + quad) * 512 + (tm * 16 + l15) * 8;
        afh[tm] = *(const bf16x8*)&Ah[off];
        afl[tm] = *(const bf16x8*)&Al[off];
      }
      #pragma unroll
      for (int tm = 0; tm < 4; ++tm)
        #pragma unroll
        for (int tn = 0; tn < 4; ++tn) {
          acc[tm][tn] = __builtin_amdgcn_mfma_f32_16x16x32_bf16(afh[tm], bh[ks][tn],  acc[tm][tn], 0, 0, 0);
          acc[tm][tn] = __builtin_amdgcn_mfma_f32_16x16x32_bf16(afh[tm], blr[ks][tn], acc[tm][tn], 0, 0, 0);
          acc[tm][tn] = __builtin_amdgcn_mfma_f32_16x16x32_bf16(afl[tm], bh[ks][tn],  acc[tm][tn], 0, 0, 0);
        }
    }

    #pragma unroll
    for (int tn = 0; tn < 4; ++tn) {
      #pragma unroll
      for (int tm = 0; tm < 4; ++tm) {
        #pragma unroll
        for (int r = 0; r < 4; ++r) {
          int pt = mb + tm * 16 + (quad << 2) + r;
          float v = acc[tm][tn][r];
          if (pt < P && v > runM[tn]) { runM[tn] = v; runI[tn] = pt; }
        }
      }
    }
  }

  #pragma unroll
  for (int tn = 0; tn < 4; ++tn) {
    float rM = runM[tn]; int rI = runI[tn];
    #pragma unroll
    for (int mk = 16; mk <= 32; mk <<= 1) {
      float v2 = __shfl_xor(rM, mk, 64);
      int   i2 = __shfl_xor(rI, mk, 64);
      if (v2 > rM || (v2 == rM && i2 < rI)) { rM = v2; rI = i2; }
    }
    if (quad == 0) {
      int ch = nc * 256 + wv * 64 + tn * 16 + l15;
      size_t o = ((size_t)b * 1024 + ch) * (size_t)PS + ps;
      pmax[o] = rM; pidx[o] = rI;
    }
  }
}

// ---------------------------------------------------------------------------
// K3: reduce PS partials -> per-channel argmax (BN sign test), used bitmap,
// prefix-select first 600 unused indices.
// ---------------------------------------------------------------------------
__global__ __launch_bounds__(256) void k3_select(
    const float* __restrict__ pmax, const int* __restrict__ pidx, int PS,
    const float* __restrict__ g5, const float* __restrict__ b5,
    const float* __restrict__ m5, const float* __restrict__ v5,
    int* __restrict__ sel)
{
  __shared__ unsigned char used[8192];
  __shared__ int cnts[256];
  __shared__ int pref[256];
  const int b = blockIdx.x, tid = threadIdx.x;

  #pragma unroll
  for (int i = 0; i < 8; ++i) ((int*)used)[i * 256 + tid] = 0;
  __syncthreads();

  for (int ch = tid; ch < 1024; ch += 256) {
    const float* pm = pmax + (((size_t)b << 10) + ch) * PS;
    const int*   pi = pidx + (((size_t)b << 10) + ch) * PS;
    float bm = pm[0]; int bi = pi[0];
    for (int s2 = 1; s2 < PS; ++s2) {
      float v = pm[s2]; int ii = pi[s2];
      if (v > bm || (v == bm && ii < bi)) { bm = v; bi = ii; }
    }
    float s5 = g5[ch] / sqrtf(v5[ch] + EPSBN);
    float z = fmaf(bm, s5, b5[ch] - m5[ch] * s5);
    int idx = (z > 0.f) ? (bi & 8191) : 0;
    used[idx] = 1;
  }
  __syncthreads();

  const int base = tid << 5;
  int c = 0;
  #pragma unroll
  for (int i = 0; i < 32; ++i) c += (used[base + i] == 0) ? 1 : 0;
  cnts[tid] = c;
  __syncthreads();
  if (tid == 0) {
    int r = 0;
    for (int i = 0; i < 256; ++i) { pref[i] = r; r += cnts[i]; }
  }
  __syncthreads();
  int rank = pref[tid];
  for (int i = 0; i < 32; ++i) {
    int n0 = base + i;
    if (!used[n0]) { if (rank < 600) sel[b * 600 + rank] = n0; ++rank; }
  }
}

// ---------------------------------------------------------------------------
// K6a: fc1 over 64 blocks (16 b x 4 row-chunks of 128).
// ---------------------------------------------------------------------------
__global__ __launch_bounds__(256) void k6a_fc1(
    const float* __restrict__ pmax2, int PS2,
    const float* __restrict__ g5, const float* __restrict__ b5,
    const float* __restrict__ m5, const float* __restrict__ v5,
    const float* __restrict__ L1w,
    const float* __restrict__ g6, const float* __restrict__ b6,
    const float* __restrict__ m6, const float* __restrict__ v6,
    float* __restrict__ h6buf)
{
  __shared__ float pooled[1024];
  __shared__ float part[128][2];
  const int b = blockIdx.x >> 2, rc = blockIdx.x & 3;
  const int tid = threadIdx.x;

  for (int ch = tid; ch < 1024; ch += 256) {
    const float* pm = pmax2 + (((size_t)b << 10) + ch) * PS2;
    float raw = pm[0];
    for (int s2 = 1; s2 < PS2; ++s2) raw = fmaxf(raw, pm[s2]);
    float s5 = g5[ch] / sqrtf(v5[ch] + EPSBN);
    pooled[ch] = fmaxf(0.f, fmaf(raw, s5, b5[ch] - m5[ch] * s5));
  }
  __syncthreads();

  const int rl = tid & 127;
  const int hf = tid >> 7;
  const int o  = rc * 128 + rl;
  float a0 = 0.f, a1 = 0.f, a2 = 0.f, a3 = 0.f;
  const int j0 = hf * 512;
  for (int j = j0; j < j0 + 512; j += 8) {
    float4 w0 = *(const float4*)&L1w[(size_t)o * 1024 + j];
    float4 w1 = *(const float4*)&L1w[(size_t)o * 1024 + j + 4];
    float4 p0 = *(const float4*)&pooled[j];
    float4 p1 = *(const float4*)&pooled[j + 4];
    a0 = fmaf(w0.x, p0.x, a0); a1 = fmaf(w0.y, p0.y, a1);
    a2 = fmaf(w0.z, p0.z, a2); a3 = fmaf(w0.w, p0.w, a3);
    a0 = fmaf(w1.x, p1.x, a0); a1 = fmaf(w1.y, p1.y, a1);
    a2 = fmaf(w1.z, p1.z, a2); a3 = fmaf(w1.w, p1.w, a3);
  }
  part[rl][hf] = (a0 + a1) + (a2 + a3);
  __syncthreads();

  if (tid < 128) {
    int oo = rc * 128 + tid;
    float acc = part[tid][0] + part[tid][1];
    float s6 = g6[oo] / sqrtf(v6[oo] + EPSBN);
    h6buf[b * 512 + oo] = fmaxf(0.f, fmaf(acc, s6, b6[oo] - m6[oo] * s6));
  }
}

// ---------------------------------------------------------------------------
// K6b: fc2 -> logits.
// ---------------------------------------------------------------------------
__global__ __launch_bounds__(64) void k6b_fc2(
    const float* __restrict__ h6buf,
    const float* __restrict__ L2w, const float* __restrict__ L2b,
    float* __restrict__ out)
{
  const int b = blockIdx.x, tid = threadIdx.x;
  if (tid < 40) {
    const float* h6 = h6buf + b * 512;
    float acc = L2b[tid];
    for (int j = 0; j < 512; j += 4) {
      float4 wv = *(const float4*)&L2w[(size_t)tid * 512 + j];
      float4 hv = *(const float4*)&h6[j];
      acc = fmaf(wv.x, hv.x, acc);
      acc = fmaf(wv.y, hv.y, acc);
      acc = fmaf(wv.z, hv.z, acc);
      acc = fmaf(wv.w, hv.w, acc);
    }
    out[b * 40 + tid] = acc;
  }
}

// ---------------------------------------------------------------------------
// launcher
// ---------------------------------------------------------------------------
extern "C" void kernel_launch(void* const* d_in, const int* in_sizes, int n_in,
                              void* d_out, int out_size, void* d_ws, size_t ws_size,
                              hipStream_t stream)
{
  (void)in_sizes; (void)n_in; (void)out_size; (void)ws_size;
  const float* x   = (const float*)d_in[0];
  const float* W1  = (const float*)d_in[1];
  const float* g1  = (const float*)d_in[2];
  const float* b1  = (const float*)d_in[3];
  const float* m1  = (const float*)d_in[4];
  const float* v1  = (const float*)d_in[5];
  const float* W2  = (const float*)d_in[6];
  const float* g2  = (const float*)d_in[7];
  const float* b2  = (const float*)d_in[8];
  const float* m2  = (const float*)d_in[9];
  const float* v2  = (const float*)d_in[10];
  const float* W3  = (const float*)d_in[11];
  const float* g3  = (const float*)d_in[12];
  const float* b3  = (const float*)d_in[13];
  const float* m3  = (const float*)d_in[14];
  const float* v3  = (const float*)d_in[15];
  const float* W4  = (const float*)d_in[16];
  const float* g4  = (const float*)d_in[17];
  const float* b4  = (const float*)d_in[18];
  const float* m4  = (const float*)d_in[19];
  const float* v4  = (const float*)d_in[20];
  const float* W5  = (const float*)d_in[21];
  const float* g5  = (const float*)d_in[22];
  const float* b5  = (const float*)d_in[23];
  const float* m5  = (const float*)d_in[24];
  const float* v5  = (const float*)d_in[25];
  const float* L1w = (const float*)d_in[26];
  const float* g6  = (const float*)d_in[27];
  const float* b6  = (const float*)d_in[28];
  const float* m6  = (const float*)d_in[29];
  const float* v6  = (const float*)d_in[30];
  const float* L2w = (const float*)d_in[31];
  const float* L2b = (const float*)d_in[32];

  char* ws = (char*)d_ws;
  float* Wf    = (float*)(ws + 0);            //    68,864 B (pad 69,632)
  u16*   W5h   = (u16*)(ws + 69632);          //   262,144 B
  u16*   W5l   = (u16*)(ws + 331776);         //   262,144 B
  u16*   W2h   = (u16*)(ws + 593920);         //     8,192 B
  u16*   W2l   = (u16*)(ws + 602112);         //     8,192 B
  u16*   W3h   = (u16*)(ws + 610304);         //     8,192 B
  u16*   W3l   = (u16*)(ws + 618496);         //     8,192 B
  u16*   W4h   = (u16*)(ws + 626688);         //    16,384 B
  u16*   W4l   = (u16*)(ws + 643072);         //    16,384 B
  u16*   H4a   = (u16*)(ws + 659456);         // 33,554,432 B
  u16*   H4b   = (u16*)(ws + 34213888);       // 33,554,432 B
  float* pmax  = (float*)(ws + 67768320);     // 1,048,576 B
  int*   pidx  = (int*)(ws + 68816896);       // 1,048,576 B
  float* pmax2 = (float*)(ws + 69865472);     //   655,360 B
  int*   pidx2 = (int*)(ws + 70520832);       //   655,360 B
  int*   sel   = (int*)(ws + 71176192);       //    38,400 B
  float* h6buf = (float*)(ws + 71215104);     //    32,768 B
  // total ~71.2 MB

  k0_prep<<<578, 256, 0, stream>>>(W5, W1, W2, W3, W4,
                                   g1, b1, m1, v1, g2, b2, m2, v2,
                                   g3, b3, m3, v3, g4, b4, m4, v4,
                                   W5h, W5l, W2h, W2l, W3h, W3l, W4h, W4l, Wf);
  k1_conv<<<1024, 128, 0, stream>>>(x, Wf, W2h, W2l, W3h, W3l, W4h, W4l,
                                    H4a, H4b);
  k2a_gemm<<<1024, 256, 0, stream>>>(H4a, H4b, W5h, W5l, pmax, pidx);
  k3_select<<<16, 256, 0, stream>>>(pmax, pidx, 16, g5, b5, m5, v5, sel);
  k2_gemm<<<640, 256, 0, stream>>>(H4a, H4b, W5h, W5l, sel,
                                   600, 10, 1, pmax2, pidx2);
  k6a_fc1<<<64, 256, 0, stream>>>(pmax2, 10, g5, b5, m5, v5, L1w,
                                  g6, b6, m6, v6, h6buf);
  k6b_fc2<<<16, 64, 0, stream>>>(h6buf, L2w, L2b, (float*)d_out);
}

// Round 13
// 290.620 us; speedup vs baseline: 1.0256x; 1.0256x over previous
//
#include <hip/hip_runtime.h>
#include <cstdint>

typedef uint16_t u16;
typedef unsigned int u32;
typedef __attribute__((ext_vector_type(8))) short bf16x8;
typedef __attribute__((ext_vector_type(4))) float f32x4;

union U4V { uint4 u; bf16x8 v; };

#define EPSBN 1e-5f

__device__ __forceinline__ float bf2f(u16 h) {
  return __uint_as_float(((unsigned)h) << 16);
}
__device__ __forceinline__ u16 f2bf(float f) {
  unsigned u = __float_as_uint(f);
  unsigned r = u + 0x7fffu + ((u >> 16) & 1u);
  return (u16)(r >> 16);
}

// ---------------------------------------------------------------------------
// K0: W5 -> bf16 hi/lo fragment-linear; W2/W3/W4 -> fragment-linear hi/lo
// for k1's MFMA layers; W1 + folded BN scale/shift into Wf.
// ---------------------------------------------------------------------------
__global__ void k0_prep(const float* __restrict__ W5,
                        const float* __restrict__ W1, const float* __restrict__ W2,
                        const float* __restrict__ W3, const float* __restrict__ W4,
                        const float* g1, const float* b1, const float* m1, const float* v1,
                        const float* g2, const float* b2, const float* m2, const float* v2,
                        const float* g3, const float* b3, const float* m3, const float* v3,
                        const float* g4, const float* b4, const float* m4, const float* v4,
                        u16* __restrict__ W5h, u16* __restrict__ W5l,
                        u16* __restrict__ W2h, u16* __restrict__ W2l,
                        u16* __restrict__ W3h, u16* __restrict__ W3l,
                        u16* __restrict__ W4h, u16* __restrict__ W4l,
                        float* __restrict__ Wf)
{
  int idx = blockIdx.x * 256 + threadIdx.x;
  if (idx < 131072) {
    int f = idx;
    int j = f & 7, l15 = (f >> 3) & 15, quad = (f >> 7) & 3, ks = (f >> 9) & 3, g = f >> 11;
    float w = W5[(g * 16 + l15) * 128 + ks * 32 + quad * 8 + j];
    u16 hi = f2bf(w);
    W5h[f] = hi;
    W5l[f] = f2bf(w - bf2f(hi));
    return;
  }
  int j = idx - 131072;
  if (j < 16384) {
    const float* src; u16 *dh, *dl; int f;
    if (j < 4096)      { src = W2; dh = W2h; dl = W2l; f = j; }
    else if (j < 8192) { src = W3; dh = W3h; dl = W3l; f = j - 4096; }
    else               { src = W4; dh = W4h; dl = W4l; f = j - 8192; }
    int jj = f & 7;
    int lane = (f >> 3) & 63;
    int t = f >> 9;            // tn*2 + ks
    int ks = t & 1, tn = t >> 1;
    int l15 = lane & 15, quad = lane >> 4;
    float w = src[(tn * 16 + l15) * 64 + ks * 32 + quad * 8 + jj];
    u16 hi = f2bf(w);
    dh[f] = hi;
    dl[f] = f2bf(w - bf2f(hi));
  } else if (j < 16576) {
    Wf[j] = W1[j - 16384];
  } else if (j < 16896) {
    int t = j - 16576;
    const float *g, *bb, *mm, *vv; int ch;
    if (t < 64)       { g = g1; bb = b1; mm = m1; vv = v1; ch = t;       }
    else if (t < 128) { g = g2; bb = b2; mm = m2; vv = v2; ch = t - 64;  }
    else if (t < 192) { g = g3; bb = b3; mm = m3; vv = v3; ch = t - 128; }
    else              { g = g4; bb = b4; mm = m4; vv = v4; ch = t - 192; }
    float s = g[ch] / sqrtf(vv[ch] + EPSBN);
    Wf[16576 + t] = s;
    Wf[16896 + t] = bb[ch] - mm[ch] * s;
  }
}

// ---------------------------------------------------------------------------
// K1 v3: layers 2-4 on MFMA (layouts unchanged from r10-verified version).
// VALU diet: (a) truncation hi/lo split (valid since post-relu v>=0; pair
// error 2^-16), 4 VALU/elem vs ~12; (b) split-plane LDS transpose
// T[row][0..63]=hi, T[row][64..127]=lo (u16, row stride 136) -> fragment
// loads and H4 stores are direct b128, zero unpack.
// ---------------------------------------------------------------------------
__global__ __launch_bounds__(128, 2) void k1_conv(
    const float* __restrict__ x, const float* __restrict__ Wf,
    const u16* __restrict__ W2h, const u16* __restrict__ W2l,
    const u16* __restrict__ W3h, const u16* __restrict__ W3l,
    const u16* __restrict__ W4h, const u16* __restrict__ W4l,
    u16* __restrict__ H4a, u16* __restrict__ H4b)
{
  __shared__ u16 T[2][64 * 136];   // per-wave planes: hi cols 0-63, lo 64-127
  __shared__ float P1[832];
  const int tid = threadIdx.x;
  const int w = tid >> 6, lane = tid & 63;
  const int l15 = lane & 15, quad = lane >> 4;
  const int base = blockIdx.x * 128 + w * 64;
  const int b = base >> 13, n0 = base & 8191;

  for (int i = tid; i < 832; i += 128)
    P1[i] = (i < 192) ? Wf[16384 + i]
          : (i < 512) ? Wf[16576 + (i - 192)]
                      : Wf[16896 + (i - 512)];
  __syncthreads();
  u16* Tw = &T[w][0];
  const float* SCs = &P1[192];
  const float* SHs = &P1[512];
  const f32x4 vzero = {0.f, 0.f, 0.f, 0.f};

  // ---- L1 (3 -> 64), fp32 -> A-frags in regs (trunc split)
  float xl0 = x[(b * 3 + 0) * 8192 + n0 + lane];
  float xl1 = x[(b * 3 + 1) * 8192 + n0 + lane];
  float xl2 = x[(b * 3 + 2) * 8192 + n0 + lane];
  float xs0[4], xs1[4], xs2[4];
  #pragma unroll
  for (int tm = 0; tm < 4; ++tm) {
    xs0[tm] = __shfl(xl0, tm * 16 + l15, 64);
    xs1[tm] = __shfl(xl1, tm * 16 + l15, 64);
    xs2[tm] = __shfl(xl2, tm * 16 + l15, 64);
  }
  bf16x8 ah[2][4], al[2][4];
  #pragma unroll
  for (int ks = 0; ks < 2; ++ks)
    #pragma unroll
    for (int tm = 0; tm < 4; ++tm) {
      u32 hp[4], lp[4];
      #pragma unroll
      for (int jp = 0; jp < 4; ++jp) {
        int ch0 = ks * 32 + quad * 8 + jp * 2;
        float c0 = P1[ch0 * 3] * xs0[tm];
        c0 = fmaf(P1[ch0 * 3 + 1], xs1[tm], c0);
        c0 = fmaf(P1[ch0 * 3 + 2], xs2[tm], c0);
        float v0 = fmaxf(0.f, fmaf(c0, SCs[ch0], SHs[ch0]));
        int ch1 = ch0 + 1;
        float c1 = P1[ch1 * 3] * xs0[tm];
        c1 = fmaf(P1[ch1 * 3 + 1], xs1[tm], c1);
        c1 = fmaf(P1[ch1 * 3 + 2], xs2[tm], c1);
        float v1 = fmaxf(0.f, fmaf(c1, SCs[ch1], SHs[ch1]));
        u32 u0 = __float_as_uint(v0), u1 = __float_as_uint(v1);
        float e0 = v0 - __uint_as_float(u0 & 0xffff0000u);
        float e1 = v1 - __uint_as_float(u1 & 0xffff0000u);
        hp[jp] = (u0 >> 16) | (u1 & 0xffff0000u);
        lp[jp] = (__float_as_uint(e0) >> 16) | (__float_as_uint(e1) & 0xffff0000u);
      }
      U4V th, tl;
      th.u.x = hp[0]; th.u.y = hp[1]; th.u.z = hp[2]; th.u.w = hp[3];
      tl.u.x = lp[0]; tl.u.y = lp[1]; tl.u.z = lp[2]; tl.u.w = lp[3];
      ah[ks][tm] = th.v; al[ks][tm] = tl.v;
    }

  // ---- L2 (64 -> 64): MFMA, epilogue -> T planes
  {
    f32x4 acc[4][4];
    #pragma unroll
    for (int tm = 0; tm < 4; ++tm)
      #pragma unroll
      for (int tn = 0; tn < 4; ++tn) acc[tm][tn] = vzero;
    #pragma unroll
    for (int ks = 0; ks < 2; ++ks) {
      bf16x8 bh[4], bl[4];
      #pragma unroll
      for (int tn = 0; tn < 4; ++tn) {
        int idx = ((tn * 2 + ks) * 64 + lane) * 8;
        bh[tn] = *(const bf16x8*)&W2h[idx];
        bl[tn] = *(const bf16x8*)&W2l[idx];
      }
      #pragma unroll
      for (int tm = 0; tm < 4; ++tm)
        #pragma unroll
        for (int tn = 0; tn < 4; ++tn) {
          acc[tm][tn] = __builtin_amdgcn_mfma_f32_16x16x32_bf16(ah[ks][tm], bh[tn], acc[tm][tn], 0, 0, 0);
          acc[tm][tn] = __builtin_amdgcn_mfma_f32_16x16x32_bf16(ah[ks][tm], bl[tn], acc[tm][tn], 0, 0, 0);
          acc[tm][tn] = __builtin_amdgcn_mfma_f32_16x16x32_bf16(al[ks][tm], bh[tn], acc[tm][tn], 0, 0, 0);
        }
    }
    #pragma unroll
    for (int tn = 0; tn < 4; ++tn) {
      int ch = tn * 16 + l15;
      float sc = SCs[64 + ch], sh = SHs[64 + ch];
      #pragma unroll
      for (int tm = 0; tm < 4; ++tm)
        #pragma unroll
        for (int r = 0; r < 4; ++r) {
          float v = fmaxf(0.f, fmaf(acc[tm][tn][r], sc, sh));
          u32 uv = __float_as_uint(v);
          float e = v - __uint_as_float(uv & 0xffff0000u);
          int row = (tm * 16 + quad * 4 + r) * 136;
          Tw[row + ch]      = (u16)(uv >> 16);
          Tw[row + 64 + ch] = (u16)(__float_as_uint(e) >> 16);
        }
    }
  }

  // ---- L3 (64 -> 64): frags direct from planes, MFMA, epilogue -> planes
  #pragma unroll
  for (int ks = 0; ks < 2; ++ks)
    #pragma unroll
    for (int tm = 0; tm < 4; ++tm) {
      int o = (tm * 16 + l15) * 136 + ks * 32 + quad * 8;
      ah[ks][tm] = *(const bf16x8*)&Tw[o];
      al[ks][tm] = *(const bf16x8*)&Tw[o + 64];
    }
  {
    f32x4 acc[4][4];
    #pragma unroll
    for (int tm = 0; tm < 4; ++tm)
      #pragma unroll
      for (int tn = 0; tn < 4; ++tn) acc[tm][tn] = vzero;
    #pragma unroll
    for (int ks = 0; ks < 2; ++ks) {
      bf16x8 bh[4], bl[4];
      #pragma unroll
      for (int tn = 0; tn < 4; ++tn) {
        int idx = ((tn * 2 + ks) * 64 + lane) * 8;
        bh[tn] = *(const bf16x8*)&W3h[idx];
        bl[tn] = *(const bf16x8*)&W3l[idx];
      }
      #pragma unroll
      for (int tm = 0; tm < 4; ++tm)
        #pragma unroll
        for (int tn = 0; tn < 4; ++tn) {
          acc[tm][tn] = __builtin_amdgcn_mfma_f32_16x16x32_bf16(ah[ks][tm], bh[tn], acc[tm][tn], 0, 0, 0);
          acc[tm][tn] = __builtin_amdgcn_mfma_f32_16x16x32_bf16(ah[ks][tm], bl[tn], acc[tm][tn], 0, 0, 0);
          acc[tm][tn] = __builtin_amdgcn_mfma_f32_16x16x32_bf16(al[ks][tm], bh[tn], acc[tm][tn], 0, 0, 0);
        }
    }
    #pragma unroll
    for (int tn = 0; tn < 4; ++tn) {
      int ch = tn * 16 + l15;
      float sc = SCs[128 + ch], sh = SHs[128 + ch];
      #pragma unroll
      for (int tm = 0; tm < 4; ++tm)
        #pragma unroll
        for (int r = 0; r < 4; ++r) {
          float v = fmaxf(0.f, fmaf(acc[tm][tn][r], sc, sh));
          u32 uv = __float_as_uint(v);
          float e = v - __uint_as_float(uv & 0xffff0000u);
          int row = (tm * 16 + quad * 4 + r) * 136;
          Tw[row + ch]      = (u16)(uv >> 16);
          Tw[row + 64 + ch] = (u16)(__float_as_uint(e) >> 16);
        }
    }
  }

  // ---- L4 (64 -> 128): frags from planes, two halves of 64 outputs
  #pragma unroll
  for (int ks = 0; ks < 2; ++ks)
    #pragma unroll
    for (int tm = 0; tm < 4; ++tm) {
      int o = (tm * 16 + l15) * 136 + ks * 32 + quad * 8;
      ah[ks][tm] = *(const bf16x8*)&Tw[o];
      al[ks][tm] = *(const bf16x8*)&Tw[o + 64];
    }
  for (int half = 0; half < 2; ++half) {
    f32x4 acc[4][4];
    #pragma unroll
    for (int tm = 0; tm < 4; ++tm)
      #pragma unroll
      for (int tn = 0; tn < 4; ++tn) acc[tm][tn] = vzero;
    #pragma unroll
    for (int ks = 0; ks < 2; ++ks) {
      bf16x8 bh[4], bl[4];
      #pragma unroll
      for (int tn = 0; tn < 4; ++tn) {
        int idx = (((half * 4 + tn) * 2 + ks) * 64 + lane) * 8;
        bh[tn] = *(const bf16x8*)&W4h[idx];
        bl[tn] = *(const bf16x8*)&W4l[idx];
      }
      #pragma unroll
      for (int tm = 0; tm < 4; ++tm)
        #pragma unroll
        for (int tn = 0; tn < 4; ++tn) {
          acc[tm][tn] = __builtin_amdgcn_mfma_f32_16x16x32_bf16(ah[ks][tm], bh[tn], acc[tm][tn], 0, 0, 0);
          acc[tm][tn] = __builtin_amdgcn_mfma_f32_16x16x32_bf16(ah[ks][tm], bl[tn], acc[tm][tn], 0, 0, 0);
          acc[tm][tn] = __builtin_amdgcn_mfma_f32_16x16x32_bf16(al[ks][tm], bh[tn], acc[tm][tn], 0, 0, 0);
        }
    }
    #pragma unroll
    for (int tn = 0; tn < 4; ++tn) {
      int ch = half * 64 + tn * 16 + l15;
      float sc = SCs[192 + ch], sh = SHs[192 + ch];
      #pragma unroll
      for (int tm = 0; tm < 4; ++tm)
        #pragma unroll
        for (int r = 0; r < 4; ++r) {
          float v = fmaxf(0.f, fmaf(acc[tm][tn][r], sc, sh));
          u32 uv = __float_as_uint(v);
          float e = v - __uint_as_float(uv & 0xffff0000u);
          int row = (tm * 16 + quad * 4 + r) * 136;
          Tw[row + tn * 16 + l15]      = (u16)(uv >> 16);
          Tw[row + 64 + tn * 16 + l15] = (u16)(__float_as_uint(e) >> 16);
        }
    }
    // store this half: lane = point row, direct b128 from planes
    #pragma unroll
    for (int kg = 0; kg < 8; ++kg) {
      uint4 hu = *(const uint4*)&Tw[lane * 136 + kg * 8];
      uint4 lu = *(const uint4*)&Tw[lane * 136 + 64 + kg * 8];
      size_t e = ((size_t)(b * 16 + half * 8 + kg) * 8192 + n0 + lane) * 8;
      *(uint4*)&H4a[e] = hu;
      *(uint4*)&H4b[e] = lu;
    }
  }
}

// ---------------------------------------------------------------------------
// K2a (r12 verbatim): 2-tile barrier amortization, chunk-major LDS
// (0 conflicts), Bh+Bl register-stationary, XCD swizzle, no atomics.
// ---------------------------------------------------------------------------
__global__ __launch_bounds__(256, 2) void k2a_gemm(
    const u16* __restrict__ H4a, const u16* __restrict__ H4b,
    const u16* __restrict__ W5h, const u16* __restrict__ W5l,
    float* __restrict__ pmax, int* __restrict__ pidx)
{
  __shared__ u16 AA[2][2][16 * 512];

  const int blk = blockIdx.x;
  const int nc = (blk >> 3) & 3;
  const int p  = ((blk >> 5) << 3) + (blk & 7);
  const int b  = p >> 4;
  const int ps = p & 15;
  const int tid = threadIdx.x;
  const int lane = tid & 63, wv = tid >> 6;
  const int l15 = lane & 15, quad = lane >> 4;

  bf16x8 bh[4][4], blr[4][4];
  #pragma unroll
  for (int ks = 0; ks < 4; ++ks)
    #pragma unroll
    for (int tn = 0; tn < 4; ++tn) {
      int g = nc * 16 + wv * 4 + tn;
      size_t widx = (size_t)(g * 4 + ks) * 512 + lane * 8;
      bh[ks][tn]  = *(const bf16x8*)&W5h[widx];
      blr[ks][tn] = *(const bf16x8*)&W5l[widx];
    }

  const u16* pa[4];
  const u16* pb[4];
  #pragma unroll
  for (int i = 0; i < 4; ++i) {
    int c = i * 4 + wv;
    size_t e = ((size_t)(b * 16 + c) * 8192 + ps * 512 + lane) * 8;
    pa[i] = H4a + e;
    pb[i] = H4b + e;
  }

  float runM[4]; int runI[4];
  #pragma unroll
  for (int tn = 0; tn < 4; ++tn) { runM[tn] = -3.4e38f; runI[tn] = 0; }

  const f32x4 vzero = {0.f, 0.f, 0.f, 0.f};

  for (int tp = 0; tp < 4; ++tp) {
    __syncthreads();
    #pragma unroll
    for (int u = 0; u < 2; ++u) {
      #pragma unroll
      for (int i = 0; i < 4; ++i) {
        int c = i * 4 + wv;
        uint4 va = *(const uint4*)(pa[i] + u * 512);
        uint4 vb = *(const uint4*)(pb[i] + u * 512);
        *(uint4*)&AA[u][0][c * 512 + lane * 8] = va;
        *(uint4*)&AA[u][1][c * 512 + lane * 8] = vb;
      }
    }
    __syncthreads();

    #pragma unroll
    for (int u = 0; u < 2; ++u) {
      const int mb = ps * 512 + tp * 128 + u * 64;
      f32x4 acc[4][4];
      #pragma unroll
      for (int tm = 0; tm < 4; ++tm)
        #pragma unroll
        for (int tn = 0; tn < 4; ++tn)
          acc[tm][tn] = vzero;

      #pragma unroll
      for (int ks = 0; ks < 4; ++ks) {
        bf16x8 afh[4], afl[4];
        #pragma unroll
        for (int tm = 0; tm < 4; ++tm) {
          int off = (ks * 4 + quad) * 512 + (tm * 16 + l15) * 8;
          afh[tm] = *(const bf16x8*)&AA[u][0][off];
          afl[tm] = *(const bf16x8*)&AA[u][1][off];
        }
        #pragma unroll
        for (int tm = 0; tm < 4; ++tm)
          #pragma unroll
          for (int tn = 0; tn < 4; ++tn) {
            acc[tm][tn] = __builtin_amdgcn_mfma_f32_16x16x32_bf16(afh[tm], bh[ks][tn],  acc[tm][tn], 0, 0, 0);
            acc[tm][tn] = __builtin_amdgcn_mfma_f32_16x16x32_bf16(afh[tm], blr[ks][tn], acc[tm][tn], 0, 0, 0);
            acc[tm][tn] = __builtin_amdgcn_mfma_f32_16x16x32_bf16(afl[tm], bh[ks][tn],  acc[tm][tn], 0, 0, 0);
          }
      }

      #pragma unroll
      for (int tn = 0; tn < 4; ++tn) {
        #pragma unroll
        for (int tm = 0; tm < 4; ++tm) {
          #pragma unroll
          for (int r = 0; r < 4; ++r) {
            int pt = mb + tm * 16 + (quad << 2) + r;
            float v = acc[tm][tn][r];
            if (v > runM[tn]) { runM[tn] = v; runI[tn] = pt; }
          }
        }
      }
    }

    #pragma unroll
    for (int i = 0; i < 4; ++i) { pa[i] += 1024; pb[i] += 1024; }
  }

  #pragma unroll
  for (int tn = 0; tn < 4; ++tn) {
    float rM = runM[tn]; int rI = runI[tn];
    #pragma unroll
    for (int mk = 16; mk <= 32; mk <<= 1) {
      float v2 = __shfl_xor(rM, mk, 64);
      int   i2 = __shfl_xor(rI, mk, 64);
      if (v2 > rM || (v2 == rM && i2 < rI)) { rM = v2; rI = i2; }
    }
    if (quad == 0) {
      int ch = nc * 256 + wv * 64 + tn * 16 + l15;
      size_t o = (((size_t)b * 1024 + ch) << 4) + ps;
      pmax[o] = rM; pidx[o] = rI;
    }
  }
}

// ---------------------------------------------------------------------------
// K2 generic (gathered second pass, r12 verbatim).
// ---------------------------------------------------------------------------
__global__ __launch_bounds__(256, 2) void k2_gemm(
    const u16* __restrict__ H4a, const u16* __restrict__ H4b,
    const u16* __restrict__ W5h, const u16* __restrict__ W5l,
    const int* __restrict__ sel,
    int P, int PS, int TPB,
    float* __restrict__ pmax, int* __restrict__ pidx)
{
  __shared__ u16 Ah[16 * 512];
  __shared__ u16 Al[16 * 512];

  const int blk = blockIdx.x;
  const int nc = (blk >> 3) & 3;
  const int p  = ((blk >> 5) << 3) + (blk & 7);
  const int b  = p / PS;
  const int ps = p % PS;
  const int tid = threadIdx.x;
  const int lane = tid & 63, wv = tid >> 6;
  const int l15 = lane & 15, quad = lane >> 4;

  bf16x8 bh[4][4], blr[4][4];
  #pragma unroll
  for (int ks = 0; ks < 4; ++ks)
    #pragma unroll
    for (int tn = 0; tn < 4; ++tn) {
      int g = nc * 16 + wv * 4 + tn;
      size_t widx = (size_t)(g * 4 + ks) * 512 + lane * 8;
      bh[ks][tn]  = *(const bf16x8*)&W5h[widx];
      blr[ks][tn] = *(const bf16x8*)&W5l[widx];
    }

  float runM[4]; int runI[4];
  #pragma unroll
  for (int tn = 0; tn < 4; ++tn) { runM[tn] = -3.4e38f; runI[tn] = 0x7FFFFFFF; }

  const f32x4 vzero = {0.f, 0.f, 0.f, 0.f};

  for (int t = 0; t < TPB; ++t) {
    const int mb = (ps * TPB + t) << 6;
    if (mb >= P) break;

    __syncthreads();
    #pragma unroll
    for (int i = 0; i < 4; ++i) {
      int c = i * 4 + wv;
      uint4 va; va.x = va.y = va.z = va.w = 0u;
      uint4 vb; vb.x = vb.y = vb.z = vb.w = 0u;
      if (sel) {
        int pt = mb + lane;
        if (pt < P) {
          int n0 = sel[b * 600 + pt] & 8191;
          size_t e = ((size_t)(b * 16 + c) * 8192 + n0) * 8;
          va = *(const uint4*)&H4a[e];
          vb = *(const uint4*)&H4b[e];
        }
      } else {
        size_t e = ((size_t)(b * 16 + c) * 8192 + (mb + lane)) * 8;
        va = *(const uint4*)&H4a[e];
        vb = *(const uint4*)&H4b[e];
      }
      *(uint4*)&Ah[c * 512 + lane * 8] = va;
      *(uint4*)&Al[c * 512 + lane * 8] = vb;
    }
    __syncthreads();

    f32x4 acc[4][4];
    #pragma unroll
    for (int tm = 0; tm < 4; ++tm)
      #pragma unroll
      for (int tn = 0; tn < 4; ++tn)
        acc[tm][tn] = vzero;

    #pragma unroll
    for (int ks = 0; ks < 4; ++ks) {
      bf16x8 afh[4], afl[4];
      #pragma unroll
      for (int tm = 0; tm < 4; ++tm) {
        int off = (ks * 4 + quad) * 512 + (tm * 16 + l15) * 8;
        afh[tm] = *(const bf16x8*)&Ah[off];
        afl[tm] = *(const bf16x8*)&Al[off];
      }
      #pragma unroll
      for (int tm = 0; tm < 4; ++tm)
        #pragma unroll
        for (int tn = 0; tn < 4; ++tn) {
          acc[tm][tn] = __builtin_amdgcn_mfma_f32_16x16x32_bf16(afh[tm], bh[ks][tn],  acc[tm][tn], 0, 0, 0);
          acc[tm][tn] = __builtin_amdgcn_mfma_f32_16x16x32_bf16(afh[tm], blr[ks][tn], acc[tm][tn], 0, 0, 0);
          acc[tm][tn] = __builtin_amdgcn_mfma_f32_16x16x32_bf16(afl[tm], bh[ks][tn],  acc[tm][tn], 0, 0, 0);
        }
    }

    #pragma unroll
    for (int tn = 0; tn < 4; ++tn) {
      #pragma unroll
      for (int tm = 0; tm < 4; ++tm) {
        #pragma unroll
        for (int r = 0; r < 4; ++r) {
          int pt = mb + tm * 16 + (quad << 2) + r;
          float v = acc[tm][tn][r];
          if (pt < P && v > runM[tn]) { runM[tn] = v; runI[tn] = pt; }
        }
      }
    }
  }

  #pragma unroll
  for (int tn = 0; tn < 4; ++tn) {
    float rM = runM[tn]; int rI = runI[tn];
    #pragma unroll
    for (int mk = 16; mk <= 32; mk <<= 1) {
      float v2 = __shfl_xor(rM, mk, 64);
      int   i2 = __shfl_xor(rI, mk, 64);
      if (v2 > rM || (v2 == rM && i2 < rI)) { rM = v2; rI = i2; }
    }
    if (quad == 0) {
      int ch = nc * 256 + wv * 64 + tn * 16 + l15;
      size_t o = ((size_t)b * 1024 + ch) * (size_t)PS + ps;
      pmax[o] = rM; pidx[o] = rI;
    }
  }
}

// ---------------------------------------------------------------------------
// K3: reduce PS partials -> per-channel argmax (BN sign test), used bitmap,
// prefix-select first 600 unused indices.
// ---------------------------------------------------------------------------
__global__ __launch_bounds__(256) void k3_select(
    const float* __restrict__ pmax, const int* __restrict__ pidx, int PS,
    const float* __restrict__ g5, const float* __restrict__ b5,
    const float* __restrict__ m5, const float* __restrict__ v5,
    int* __restrict__ sel)
{
  __shared__ unsigned char used[8192];
  __shared__ int cnts[256];
  __shared__ int pref[256];
  const int b = blockIdx.x, tid = threadIdx.x;

  #pragma unroll
  for (int i = 0; i < 8; ++i) ((int*)used)[i * 256 + tid] = 0;
  __syncthreads();

  for (int ch = tid; ch < 1024; ch += 256) {
    const float* pm = pmax + (((size_t)b << 10) + ch) * PS;
    const int*   pi = pidx + (((size_t)b << 10) + ch) * PS;
    float bm = pm[0]; int bi = pi[0];
    for (int s2 = 1; s2 < PS; ++s2) {
      float v = pm[s2]; int ii = pi[s2];
      if (v > bm || (v == bm && ii < bi)) { bm = v; bi = ii; }
    }
    float s5 = g5[ch] / sqrtf(v5[ch] + EPSBN);
    float z = fmaf(bm, s5, b5[ch] - m5[ch] * s5);
    int idx = (z > 0.f) ? (bi & 8191) : 0;
    used[idx] = 1;
  }
  __syncthreads();

  const int base = tid << 5;
  int c = 0;
  #pragma unroll
  for (int i = 0; i < 32; ++i) c += (used[base + i] == 0) ? 1 : 0;
  cnts[tid] = c;
  __syncthreads();
  if (tid == 0) {
    int r = 0;
    for (int i = 0; i < 256; ++i) { pref[i] = r; r += cnts[i]; }
  }
  __syncthreads();
  int rank = pref[tid];
  for (int i = 0; i < 32; ++i) {
    int n0 = base + i;
    if (!used[n0]) { if (rank < 600) sel[b * 600 + rank] = n0; ++rank; }
  }
}

// ---------------------------------------------------------------------------
// K6a: fc1 over 64 blocks (16 b x 4 row-chunks of 128).
// ---------------------------------------------------------------------------
__global__ __launch_bounds__(256) void k6a_fc1(
    const float* __restrict__ pmax2, int PS2,
    const float* __restrict__ g5, const float* __restrict__ b5,
    const float* __restrict__ m5, const float* __restrict__ v5,
    const float* __restrict__ L1w,
    const float* __restrict__ g6, const float* __restrict__ b6,
    const float* __restrict__ m6, const float* __restrict__ v6,
    float* __restrict__ h6buf)
{
  __shared__ float pooled[1024];
  __shared__ float part[128][2];
  const int b = blockIdx.x >> 2, rc = blockIdx.x & 3;
  const int tid = threadIdx.x;

  for (int ch = tid; ch < 1024; ch += 256) {
    const float* pm = pmax2 + (((size_t)b << 10) + ch) * PS2;
    float raw = pm[0];
    for (int s2 = 1; s2 < PS2; ++s2) raw = fmaxf(raw, pm[s2]);
    float s5 = g5[ch] / sqrtf(v5[ch] + EPSBN);
    pooled[ch] = fmaxf(0.f, fmaf(raw, s5, b5[ch] - m5[ch] * s5));
  }
  __syncthreads();

  const int rl = tid & 127;
  const int hf = tid >> 7;
  const int o  = rc * 128 + rl;
  float a0 = 0.f, a1 = 0.f, a2 = 0.f, a3 = 0.f;
  const int j0 = hf * 512;
  for (int j = j0; j < j0 + 512; j += 8) {
    float4 w0 = *(const float4*)&L1w[(size_t)o * 1024 + j];
    float4 w1 = *(const float4*)&L1w[(size_t)o * 1024 + j + 4];
    float4 p0 = *(const float4*)&pooled[j];
    float4 p1 = *(const float4*)&pooled[j + 4];
    a0 = fmaf(w0.x, p0.x, a0); a1 = fmaf(w0.y, p0.y, a1);
    a2 = fmaf(w0.z, p0.z, a2); a3 = fmaf(w0.w, p0.w, a3);
    a0 = fmaf(w1.x, p1.x, a0); a1 = fmaf(w1.y, p1.y, a1);
    a2 = fmaf(w1.z, p1.z, a2); a3 = fmaf(w1.w, p1.w, a3);
  }
  part[rl][hf] = (a0 + a1) + (a2 + a3);
  __syncthreads();

  if (tid < 128) {
    int oo = rc * 128 + tid;
    float acc = part[tid][0] + part[tid][1];
    float s6 = g6[oo] / sqrtf(v6[oo] + EPSBN);
    h6buf[b * 512 + oo] = fmaxf(0.f, fmaf(acc, s6, b6[oo] - m6[oo] * s6));
  }
}

// ---------------------------------------------------------------------------
// K6b: fc2 -> logits.
// ---------------------------------------------------------------------------
__global__ __launch_bounds__(64) void k6b_fc2(
    const float* __restrict__ h6buf,
    const float* __restrict__ L2w, const float* __restrict__ L2b,
    float* __restrict__ out)
{
  const int b = blockIdx.x, tid = threadIdx.x;
  if (tid < 40) {
    const float* h6 = h6buf + b * 512;
    float acc = L2b[tid];
    for (int j = 0; j < 512; j += 4) {
      float4 wv = *(const float4*)&L2w[(size_t)tid * 512 + j];
      float4 hv = *(const float4*)&h6[j];
      acc = fmaf(wv.x, hv.x, acc);
      acc = fmaf(wv.y, hv.y, acc);
      acc = fmaf(wv.z, hv.z, acc);
      acc = fmaf(wv.w, hv.w, acc);
    }
    out[b * 40 + tid] = acc;
  }
}

// ---------------------------------------------------------------------------
// launcher
// ---------------------------------------------------------------------------
extern "C" void kernel_launch(void* const* d_in, const int* in_sizes, int n_in,
                              void* d_out, int out_size, void* d_ws, size_t ws_size,
                              hipStream_t stream)
{
  (void)in_sizes; (void)n_in; (void)out_size; (void)ws_size;
  const float* x   = (const float*)d_in[0];
  const float* W1  = (const float*)d_in[1];
  const float* g1  = (const float*)d_in[2];
  const float* b1  = (const float*)d_in[3];
  const float* m1  = (const float*)d_in[4];
  const float* v1  = (const float*)d_in[5];
  const float* W2  = (const float*)d_in[6];
  const float* g2  = (const float*)d_in[7];
  const float* b2  = (const float*)d_in[8];
  const float* m2  = (const float*)d_in[9];
  const float* v2  = (const float*)d_in[10];
  const float* W3  = (const float*)d_in[11];
  const float* g3  = (const float*)d_in[12];
  const float* b3  = (const float*)d_in[13];
  const float* m3  = (const float*)d_in[14];
  const float* v3  = (const float*)d_in[15];
  const float* W4  = (const float*)d_in[16];
  const float* g4  = (const float*)d_in[17];
  const float* b4  = (const float*)d_in[18];
  const float* m4  = (const float*)d_in[19];
  const float* v4  = (const float*)d_in[20];
  const float* W5  = (const float*)d_in[21];
  const float* g5  = (const float*)d_in[22];
  const float* b5  = (const float*)d_in[23];
  const float* m5  = (const float*)d_in[24];
  const float* v5  = (const float*)d_in[25];
  const float* L1w = (const float*)d_in[26];
  const float* g6  = (const float*)d_in[27];
  const float* b6  = (const float*)d_in[28];
  const float* m6  = (const float*)d_in[29];
  const float* v6  = (const float*)d_in[30];
  const float* L2w = (const float*)d_in[31];
  const float* L2b = (const float*)d_in[32];

  char* ws = (char*)d_ws;
  float* Wf    = (float*)(ws + 0);            //    68,864 B (pad 69,632)
  u16*   W5h   = (u16*)(ws + 69632);          //   262,144 B
  u16*   W5l   = (u16*)(ws + 331776);         //   262,144 B
  u16*   W2h   = (u16*)(ws + 593920);         //     8,192 B
  u16*   W2l   = (u16*)(ws + 602112);         //     8,192 B
  u16*   W3h   = (u16*)(ws + 610304);         //     8,192 B
  u16*   W3l   = (u16*)(ws + 618496);         //     8,192 B
  u16*   W4h   = (u16*)(ws + 626688);         //    16,384 B
  u16*   W4l   = (u16*)(ws + 643072);         //    16,384 B
  u16*   H4a   = (u16*)(ws + 659456);         // 33,554,432 B
  u16*   H4b   = (u16*)(ws + 34213888);       // 33,554,432 B
  float* pmax  = (float*)(ws + 67768320);     // 1,048,576 B
  int*   pidx  = (int*)(ws + 68816896);       // 1,048,576 B
  float* pmax2 = (float*)(ws + 69865472);     //   655,360 B
  int*   pidx2 = (int*)(ws + 70520832);       //   655,360 B
  int*   sel   = (int*)(ws + 71176192);       //    38,400 B
  float* h6buf = (float*)(ws + 71215104);     //    32,768 B
  // total ~71.2 MB

  k0_prep<<<578, 256, 0, stream>>>(W5, W1, W2, W3, W4,
                                   g1, b1, m1, v1, g2, b2, m2, v2,
                                   g3, b3, m3, v3, g4, b4, m4, v4,
                                   W5h, W5l, W2h, W2l, W3h, W3l, W4h, W4l, Wf);
  k1_conv<<<1024, 128, 0, stream>>>(x, Wf, W2h, W2l, W3h, W3l, W4h, W4l,
                                    H4a, H4b);
  k2a_gemm<<<1024, 256, 0, stream>>>(H4a, H4b, W5h, W5l, pmax, pidx);
  k3_select<<<16, 256, 0, stream>>>(pmax, pidx, 16, g5, b5, m5, v5, sel);
  k2_gemm<<<640, 256, 0, stream>>>(H4a, H4b, W5h, W5l, sel,
                                   600, 10, 1, pmax2, pidx2);
  k6a_fc1<<<64, 256, 0, stream>>>(pmax2, 10, g5, b5, m5, v5, L1w,
                                  g6, b6, m6, v6, h6buf);
  k6b_fc2<<<16, 64, 0, stream>>>(h6buf, L2w, L2b, (float*)d_out);
}